// Round 3
// baseline (821.999 us; speedup 1.0000x reference)
//
#include <hip/hip_runtime.h>
#include <math.h>

// Problem constants (fixed by setup_inputs)
#define N_TOK 16384   // B*S
#define D_DIM 2048
#define H_DIM 256
#define E_NUM 5
#define R_DIM 16
#define ER 80         // E*R

#define NCT 21        // 16 W1 col-tiles + 5 A' col-tiles (16 cols each)
#define KSTEPS 32     // 2048 / 64  (BK = 64)

typedef _Float16 half8 __attribute__((ext_vector_type(8)));
typedef float f32x4 __attribute__((ext_vector_type(4)));

// ---------------------------------------------------------------------------
// pack_w: W1[2048][256] and A'[2048][80] (A'[d][e*16+r] = A[e][d][r]) -> f16
// hi/lo fragment-linear arrays:
//   Wp[((ct*64+kg32)*64+l)*8+j] = W[kg32*32 + (l>>4)*8 + j][ct*16 + (l&15)]
// hi = f16(v), lo = f16(v - hi)  (split-f16: 3-product emulation ~ fp32).
// ---------------------------------------------------------------------------
__global__ __launch_bounds__(256) void pack_w_kernel(
    const float* __restrict__ W1, const float* __restrict__ A,
    _Float16* __restrict__ Whi, _Float16* __restrict__ Wlo) {
  const int idx = blockIdx.x * 256 + threadIdx.x;  // 21*64*64 = 86016 exact
  const int lane = idx & 63;
  const int kgct = idx >> 6;              // ct*64 + kg32, 0..1343
  const int kg = kgct & 63;
  const int ct = kgct >> 6;               // 0..20
  const int k0 = kg * 32 + ((lane >> 4) << 3);
  const int par = lane & 15;
  float v[8];
  if (ct < 16) {
    const int col = ct * 16 + par;
#pragma unroll
    for (int j = 0; j < 8; ++j) v[j] = W1[(size_t)(k0 + j) * H_DIM + col];
  } else {
    const float* Ae = A + (size_t)(ct - 16) * D_DIM * R_DIM;
#pragma unroll
    for (int j = 0; j < 8; ++j) v[j] = Ae[(size_t)(k0 + j) * R_DIM + par];
  }
  half8 hv, lv;
#pragma unroll
  for (int j = 0; j < 8; ++j) {
    const _Float16 hh = (_Float16)v[j];
    hv[j] = hh;
    lv[j] = (_Float16)(v[j] - (float)hh);
  }
  ((half8*)Whi)[(size_t)kgct * 64 + lane] = hv;
  ((half8*)Wlo)[(size_t)kgct * 64 + lane] = lv;
}

// ---------------------------------------------------------------------------
// xgemm: grid (N_TOK/64, 3). MFMA 16x16x32 f16, split-f16 3-product
// (al*bh + ah*bl + ah*bh; the ll term ~2^-22 is dropped).
//   y in {0,1}: silu(x@W1+b1) cols [y*128,+128) stay IN REGISTERS; epilogue
//               projects through W2, reduces across lanes (shfl) and waves
//               (LDS), stores partial logits plog[y][tok][5] — plain stores,
//               NO cross-XCD atomics (round-2's atomicAdd cost ~50MB of HBM
//               line-bounce traffic).
//   y == 2   : P[:, 0..79] = x @ A'  (fp32; scaled later in combine)
// Weight fragments are register double-buffered one kg32 half-step ahead so
// MFMAs never wait on a just-issued L2 load. x staged fp32->f16 hi/lo in LDS,
// double buffered, XOR swizzle row'=row^kq (conflict-free both sides).
// ---------------------------------------------------------------------------
__global__ __launch_bounds__(256, 3) void xgemm_kernel(
    const float* __restrict__ x, const float* __restrict__ b1,
    const _Float16* __restrict__ Whi, const _Float16* __restrict__ Wlo,
    const float* __restrict__ W2, float* __restrict__ plog,
    float* __restrict__ P) {
  __shared__ _Float16 lds[2][2][8][64][8];  // [buf][hi/lo][kq][row'][8] = 32 KB
  __shared__ float w2s[H_DIM * E_NUM];      // 5 KB, epilogue only
  __shared__ float plbuf[4][64][E_NUM];     // 5 KB, cross-wave logit reduce
  const int t = threadIdx.x;
  const int tok0 = blockIdx.x * 64;
  const int y = blockIdx.y;
  const int lane = t & 63;
  const int w = t >> 6;          // wave 0..3
  const int sr = t >> 2;         // staging row 0..63
  const int q = t & 3;           // staging 16-float chunk 0..3
  const int lq = lane >> 4;      // lane k-quarter
  const int lp = lane & 15;      // lane parallel index

  const float* xrow = x + (size_t)(tok0 + sr) * D_DIM + (q << 4);

  // prologue: stage kg=0 into buf 0
  {
    float xv[16];
    *(float4*)&xv[0] = *(const float4*)(xrow);
    *(float4*)&xv[4] = *(const float4*)(xrow + 4);
    *(float4*)&xv[8] = *(const float4*)(xrow + 8);
    *(float4*)&xv[12] = *(const float4*)(xrow + 12);
#pragma unroll
    for (int hf = 0; hf < 2; ++hf) {
      half8 hv, lv;
#pragma unroll
      for (int j = 0; j < 8; ++j) {
        const float v = xv[(hf << 3) + j];
        const _Float16 hh = (_Float16)v;
        hv[j] = hh;
        lv[j] = (_Float16)(v - (float)hh);
      }
      const int kq = (q << 1) + hf;
      *(half8*)&lds[0][0][kq][sr ^ kq][0] = hv;
      *(half8*)&lds[0][1][kq][sr ^ kq][0] = lv;
    }
  }

  const half8* WH = (const half8*)Whi;
  const half8* WL = (const half8*)Wlo;

  if (y < 2) {
    f32x4 acc[4][2];
#pragma unroll
    for (int i = 0; i < 4; ++i)
#pragma unroll
      for (int j = 0; j < 2; ++j) acc[i][j] = (f32x4)0.f;
    const int ctg0 = (y << 3) + (w << 1);  // wave owns 2 col-tiles

    // preload even-half weights for kg=0
    half8 bhE[2], blE[2], bhO[2], blO[2];
#pragma unroll
    for (int ct = 0; ct < 2; ++ct) {
      const size_t wo = ((size_t)(ctg0 + ct) * 64 + 0) * 64 + lane;
      bhE[ct] = WH[wo];
      blE[ct] = WL[wo];
    }

    int cur = 0;
    for (int kg = 0; kg < KSTEPS; ++kg) {
      __syncthreads();
      const bool more = (kg < KSTEPS - 1);
      // 1) issue odd-half weight loads (needed after the even MFMAs)
#pragma unroll
      for (int ct = 0; ct < 2; ++ct) {
        const size_t wo = ((size_t)(ctg0 + ct) * 64 + (kg << 1) + 1) * 64 + lane;
        bhO[ct] = WH[wo];
        blO[ct] = WL[wo];
      }
      // 2) issue next-kg x prefetch (consumed at body end)
      float xv[16];
      if (more) {
        const float* src = xrow + (kg + 1) * 64;
        *(float4*)&xv[0] = *(const float4*)(src);
        *(float4*)&xv[4] = *(const float4*)(src + 4);
        *(float4*)&xv[8] = *(const float4*)(src + 8);
        *(float4*)&xv[12] = *(const float4*)(src + 12);
      }
      // 3) even-half MFMAs (weights already resident from previous body)
#pragma unroll
      for (int rt = 0; rt < 4; ++rt) {
        const int r = ((rt << 4) + lp) ^ lq;
        const half8 ah = *(const half8*)&lds[cur][0][lq][r][0];
        const half8 al = *(const half8*)&lds[cur][1][lq][r][0];
#pragma unroll
        for (int ct = 0; ct < 2; ++ct) {
          acc[rt][ct] = __builtin_amdgcn_mfma_f32_16x16x32_f16(al, bhE[ct], acc[rt][ct], 0, 0, 0);
          acc[rt][ct] = __builtin_amdgcn_mfma_f32_16x16x32_f16(ah, blE[ct], acc[rt][ct], 0, 0, 0);
          acc[rt][ct] = __builtin_amdgcn_mfma_f32_16x16x32_f16(ah, bhE[ct], acc[rt][ct], 0, 0, 0);
        }
      }
      // 4) issue next even-half weight loads
      if (more) {
#pragma unroll
        for (int ct = 0; ct < 2; ++ct) {
          const size_t wo = ((size_t)(ctg0 + ct) * 64 + (kg << 1) + 2) * 64 + lane;
          bhE[ct] = WH[wo];
          blE[ct] = WL[wo];
        }
      }
      // 5) odd-half MFMAs
#pragma unroll
      for (int rt = 0; rt < 4; ++rt) {
        const int kq = 4 + lq;
        const int r = ((rt << 4) + lp) ^ kq;
        const half8 ah = *(const half8*)&lds[cur][0][kq][r][0];
        const half8 al = *(const half8*)&lds[cur][1][kq][r][0];
#pragma unroll
        for (int ct = 0; ct < 2; ++ct) {
          acc[rt][ct] = __builtin_amdgcn_mfma_f32_16x16x32_f16(al, bhO[ct], acc[rt][ct], 0, 0, 0);
          acc[rt][ct] = __builtin_amdgcn_mfma_f32_16x16x32_f16(ah, blO[ct], acc[rt][ct], 0, 0, 0);
          acc[rt][ct] = __builtin_amdgcn_mfma_f32_16x16x32_f16(ah, bhO[ct], acc[rt][ct], 0, 0, 0);
        }
      }
      // 6) stage next x tile
      if (more) {
#pragma unroll
        for (int hf = 0; hf < 2; ++hf) {
          half8 hv, lv;
#pragma unroll
          for (int j = 0; j < 8; ++j) {
            const float v = xv[(hf << 3) + j];
            const _Float16 hh = (_Float16)v;
            hv[j] = hh;
            lv[j] = (_Float16)(v - (float)hh);
          }
          const int kq = (q << 1) + hf;
          *(half8*)&lds[cur ^ 1][0][kq][sr ^ kq][0] = hv;
          *(half8*)&lds[cur ^ 1][1][kq][sr ^ kq][0] = lv;
        }
      }
      cur ^= 1;
    }

    // epilogue: silu in-register, project through W2, reduce lanes (shfl)
    // then waves (LDS), store partial logits (plain stores, deterministic).
    for (int i = t; i < H_DIM * E_NUM; i += 256) w2s[i] = W2[i];
    __syncthreads();
    const int colb = (y << 7) + (w << 5);
#pragma unroll
    for (int rt = 0; rt < 4; ++rt) {
      float pl[4][5];
#pragma unroll
      for (int rg = 0; rg < 4; ++rg)
#pragma unroll
        for (int e = 0; e < 5; ++e) pl[rg][e] = 0.f;
#pragma unroll
      for (int ct = 0; ct < 2; ++ct) {
        const int col = colb + (ct << 4) + lp;
        const float bb = b1[col];
        float w2c[5];
#pragma unroll
        for (int e = 0; e < 5; ++e) w2c[e] = w2s[col * 5 + e];
#pragma unroll
        for (int rg = 0; rg < 4; ++rg) {
          float v = acc[rt][ct][rg] + bb;
          v = v / (1.f + expf(-v));  // silu; h value, never stored
#pragma unroll
          for (int e = 0; e < 5; ++e) pl[rg][e] = fmaf(v, w2c[e], pl[rg][e]);
        }
      }
      // reduce over the 16 lp lanes (lq groups stay independent)
#pragma unroll
      for (int m = 1; m < 16; m <<= 1)
#pragma unroll
        for (int rg = 0; rg < 4; ++rg)
#pragma unroll
          for (int e = 0; e < 5; ++e) pl[rg][e] += __shfl_xor(pl[rg][e], m, 64);
      if (lp == 0) {
        const int rl0 = (rt << 4) + (lq << 2);
#pragma unroll
        for (int rg = 0; rg < 4; ++rg)
#pragma unroll
          for (int e = 0; e < 5; ++e) plbuf[w][rl0 + rg][e] = pl[rg][e];
      }
    }
    __syncthreads();
    // cross-wave sum + store: 320 values, threads 0..319 -> t<256 does all
    for (int i = t; i < 64 * E_NUM; i += 256) {
      const int row = i / E_NUM;
      const int e = i - row * E_NUM;
      const float s = plbuf[0][row][e] + plbuf[1][row][e] +
                      plbuf[2][row][e] + plbuf[3][row][e];
      plog[((size_t)y * N_TOK + tok0 + row) * E_NUM + e] = s;
    }
  } else {
    // P path: wave owns 16 rows x all 80 cols (5 col-tiles)
    f32x4 acc[5];
#pragma unroll
    for (int j = 0; j < 5; ++j) acc[j] = (f32x4)0.f;

    half8 bhE[5], blE[5], bhO[5], blO[5];
#pragma unroll
    for (int ct = 0; ct < 5; ++ct) {
      const size_t wo = ((size_t)(16 + ct) * 64 + 0) * 64 + lane;
      bhE[ct] = WH[wo];
      blE[ct] = WL[wo];
    }

    int cur = 0;
    for (int kg = 0; kg < KSTEPS; ++kg) {
      __syncthreads();
      const bool more = (kg < KSTEPS - 1);
#pragma unroll
      for (int ct = 0; ct < 5; ++ct) {
        const size_t wo = ((size_t)(16 + ct) * 64 + (kg << 1) + 1) * 64 + lane;
        bhO[ct] = WH[wo];
        blO[ct] = WL[wo];
      }
      float xv[16];
      if (more) {
        const float* src = xrow + (kg + 1) * 64;
        *(float4*)&xv[0] = *(const float4*)(src);
        *(float4*)&xv[4] = *(const float4*)(src + 4);
        *(float4*)&xv[8] = *(const float4*)(src + 8);
        *(float4*)&xv[12] = *(const float4*)(src + 12);
      }
      {  // even half: kq = lq
        const int r = ((w << 4) + lp) ^ lq;
        const half8 ah = *(const half8*)&lds[cur][0][lq][r][0];
        const half8 al = *(const half8*)&lds[cur][1][lq][r][0];
#pragma unroll
        for (int ct = 0; ct < 5; ++ct) {
          acc[ct] = __builtin_amdgcn_mfma_f32_16x16x32_f16(al, bhE[ct], acc[ct], 0, 0, 0);
          acc[ct] = __builtin_amdgcn_mfma_f32_16x16x32_f16(ah, blE[ct], acc[ct], 0, 0, 0);
          acc[ct] = __builtin_amdgcn_mfma_f32_16x16x32_f16(ah, bhE[ct], acc[ct], 0, 0, 0);
        }
      }
      if (more) {
#pragma unroll
        for (int ct = 0; ct < 5; ++ct) {
          const size_t wo = ((size_t)(16 + ct) * 64 + (kg << 1) + 2) * 64 + lane;
          bhE[ct] = WH[wo];
          blE[ct] = WL[wo];
        }
      }
      {  // odd half: kq = 4 + lq
        const int kq = 4 + lq;
        const int r = ((w << 4) + lp) ^ kq;
        const half8 ah = *(const half8*)&lds[cur][0][kq][r][0];
        const half8 al = *(const half8*)&lds[cur][1][kq][r][0];
#pragma unroll
        for (int ct = 0; ct < 5; ++ct) {
          acc[ct] = __builtin_amdgcn_mfma_f32_16x16x32_f16(al, bhO[ct], acc[ct], 0, 0, 0);
          acc[ct] = __builtin_amdgcn_mfma_f32_16x16x32_f16(ah, blO[ct], acc[ct], 0, 0, 0);
          acc[ct] = __builtin_amdgcn_mfma_f32_16x16x32_f16(ah, bhO[ct], acc[ct], 0, 0, 0);
        }
      }
      if (more) {
#pragma unroll
        for (int hf = 0; hf < 2; ++hf) {
          half8 hv, lv;
#pragma unroll
          for (int j = 0; j < 8; ++j) {
            const float v = xv[(hf << 3) + j];
            const _Float16 hh = (_Float16)v;
            hv[j] = hh;
            lv[j] = (_Float16)(v - (float)hh);
          }
          const int kq = (q << 1) + hf;
          *(half8*)&lds[cur ^ 1][0][kq][sr ^ kq][0] = hv;
          *(half8*)&lds[cur ^ 1][1][kq][sr ^ kq][0] = lv;
        }
      }
      cur ^= 1;
    }
#pragma unroll
    for (int ct = 0; ct < 5; ++ct)
#pragma unroll
      for (int rg = 0; rg < 4; ++rg) {
        const int row = tok0 + (w << 4) + (lq << 2) + rg;
        P[(size_t)row * ER + (ct << 4) + lp] = acc[ct][rg];
      }
  }
}

// ---------------------------------------------------------------------------
// combine: out = base + (scaled P)[N,80] @ B[80,2048].  Route decision fused:
// 64-thread prologue sums the two partial-logit halves + b2, computes top-2
// and normalized scales; P staged to LDS pre-scaled; inner loop reads P via
// uniform-address ds_read_b128 broadcast. acc is INITIALIZED from base (loads
// issued at kernel entry, hidden under the prologue/staging phase) so the
// epilogue is store-only.
// ---------------------------------------------------------------------------
__global__ __launch_bounds__(256, 4) void combine_kernel(
    const float* __restrict__ P, const float* __restrict__ Bm,
    const float* __restrict__ base, const float* __restrict__ plog,
    const float* __restrict__ b2, float* __restrict__ out) {
  __shared__ float Pl[64][80];  // pre-scaled P tile, 20 KB
  __shared__ float sc[64][5];   // per-token per-expert scale
  const int t = threadIdx.x;
  const int wg = __builtin_amdgcn_readfirstlane(t >> 6);  // wave-uniform
  const int c4 = ((blockIdx.x & 7) << 8) + ((t & 63) << 2);
  const int tokb = (blockIdx.x >> 3) << 6;
  const int r0 = wg << 4;

  // issue base loads first; they complete under prologue + staging
  float4 acc[16];
#pragma unroll
  for (int i = 0; i < 16; ++i)
    acc[i] = *(const float4*)(base + (size_t)(tokb + r0 + i) * D_DIM + c4);

  if (t < 64) {
    const float* p0 = plog + (size_t)(tokb + t) * E_NUM;
    const float* p1 = plog + ((size_t)N_TOK + tokb + t) * E_NUM;
    float lg[5];
#pragma unroll
    for (int e = 0; e < 5; ++e) lg[e] = p0[e] + p1[e] + b2[e];
    int e0 = 0;
#pragma unroll
    for (int e = 1; e < 5; ++e) if (lg[e] > lg[e0]) e0 = e;
    int e1 = (e0 == 0) ? 1 : 0;
#pragma unroll
    for (int e = 0; e < 5; ++e) if (e != e0 && lg[e] > lg[e1]) e1 = e;
    const float qq = expf(lg[e1] - lg[e0]);  // <= 1, stable
    const float s0 = 2.f / (1.f + qq);       // SCALING * w0_normalized
    const float s1 = qq * s0;                // SCALING * w1_normalized
#pragma unroll
    for (int e = 0; e < 5; ++e)
      sc[t][e] = (e == e0) ? s0 : ((e == e1) ? s1 : 0.f);
  }
  __syncthreads();
  {  // stage P, scaled: thread t covers row t/4, 20-float chunk (t&3)
    const int row = t >> 2;
    const int off = (t & 3) * 20;
    const float* prow = P + (size_t)(tokb + row) * ER + off;
#pragma unroll
    for (int j = 0; j < 5; ++j) {
      float4 v = *(const float4*)(prow + (j << 2));
      v.x *= sc[row][(off + (j << 2) + 0) >> 4];
      v.y *= sc[row][(off + (j << 2) + 1) >> 4];
      v.z *= sc[row][(off + (j << 2) + 2) >> 4];
      v.w *= sc[row][(off + (j << 2) + 3) >> 4];
      *(float4*)&Pl[row][off + (j << 2)] = v;
    }
  }
  __syncthreads();

  for (int k0 = 0; k0 < ER; k0 += 4) {
    const float4 bv0 = *(const float4*)(Bm + (size_t)(k0 + 0) * D_DIM + c4);
    const float4 bv1 = *(const float4*)(Bm + (size_t)(k0 + 1) * D_DIM + c4);
    const float4 bv2 = *(const float4*)(Bm + (size_t)(k0 + 2) * D_DIM + c4);
    const float4 bv3 = *(const float4*)(Bm + (size_t)(k0 + 3) * D_DIM + c4);
#pragma unroll
    for (int i = 0; i < 16; ++i) {
      float pv[4];
      *(float4*)pv = *(const float4*)&Pl[r0 + i][k0];  // uniform -> broadcast
      acc[i].x = fmaf(pv[0], bv0.x, fmaf(pv[1], bv1.x, fmaf(pv[2], bv2.x, fmaf(pv[3], bv3.x, acc[i].x))));
      acc[i].y = fmaf(pv[0], bv0.y, fmaf(pv[1], bv1.y, fmaf(pv[2], bv2.y, fmaf(pv[3], bv3.y, acc[i].y))));
      acc[i].z = fmaf(pv[0], bv0.z, fmaf(pv[1], bv1.z, fmaf(pv[2], bv2.z, fmaf(pv[3], bv3.z, acc[i].z))));
      acc[i].w = fmaf(pv[0], bv0.w, fmaf(pv[1], bv1.w, fmaf(pv[2], bv2.w, fmaf(pv[3], bv3.w, acc[i].w))));
    }
  }

#pragma unroll
  for (int i = 0; i < 16; ++i) {
    const size_t o = (size_t)(tokb + r0 + i) * D_DIM + c4;
    *(float4*)(out + o) = acc[i];
  }
}

// ---------------------------------------------------------------------------
extern "C" void kernel_launch(void* const* d_in, const int* in_sizes, int n_in,
                              void* d_out, int out_size, void* d_ws,
                              size_t ws_size, hipStream_t stream) {
  const float* x  = (const float*)d_in[0];
  const float* bo = (const float*)d_in[1];
  const float* A  = (const float*)d_in[2];
  const float* Bm = (const float*)d_in[3];
  const float* W1 = (const float*)d_in[4];
  const float* b1 = (const float*)d_in[5];
  const float* W2 = (const float*)d_in[6];
  const float* b2 = (const float*)d_in[7];
  float* out = (float*)d_out;

  char* ws = (char*)d_ws;
  float* P = (float*)ws;                                  // [N][80] f32 = 5.25 MiB
  _Float16* Whi = (_Float16*)(ws + 5242880);              // 1.31 MiB
  _Float16* Wlo = (_Float16*)(ws + 5242880 + 1376256);    // 1.31 MiB
  float* plog = (float*)(ws + 5242880 + 2 * 1376256);     // [2][N][5] = 640 KiB

  pack_w_kernel<<<336, 256, 0, stream>>>(W1, A, Whi, Wlo);
  xgemm_kernel<<<dim3(N_TOK / 64, 3), 256, 0, stream>>>(x, b1, Whi, Wlo, W2,
                                                        plog, P);
  combine_kernel<<<(N_TOK / 64) * (D_DIM / 256), 256, 0, stream>>>(
      P, Bm, bo, plog, b2, out);
}

// Round 4
// 441.977 us; speedup vs baseline: 1.8598x; 1.8598x over previous
//
#include <hip/hip_runtime.h>
#include <math.h>

// Problem constants (fixed by setup_inputs)
#define N_TOK 16384   // B*S
#define D_DIM 2048
#define H_DIM 256
#define E_NUM 5
#define R_DIM 16
#define ER 80         // E*R

#define NCT 21        // 16 W1 col-tiles + 5 A' col-tiles (16 cols each)
#define KG_N 64       // 2048 / 32  (BK = 32)

typedef _Float16 half8 __attribute__((ext_vector_type(8)));
typedef float f32x4 __attribute__((ext_vector_type(4)));

// ---------------------------------------------------------------------------
// pack_w: W1[2048][256] and A'[2048][80] (A'[d][e*16+r] = A[e][d][r]) -> f16
// hi/lo fragment-linear arrays:
//   Wp[((ct*64+kg)*64+l)*8+j] = W[kg*32 + (l>>4)*8 + j][ct*16 + (l&15)]
// hi = f16(v), lo = f16(v - hi)  (split-f16: 3-product emulation ~ fp32).
// ---------------------------------------------------------------------------
__global__ __launch_bounds__(256) void pack_w_kernel(
    const float* __restrict__ W1, const float* __restrict__ A,
    _Float16* __restrict__ Whi, _Float16* __restrict__ Wlo) {
  const int idx = blockIdx.x * 256 + threadIdx.x;  // 21*64*64 = 86016 exact
  const int lane = idx & 63;
  const int kgct = idx >> 6;              // ct*64 + kg, 0..1343
  const int kg = kgct & 63;
  const int ct = kgct >> 6;               // 0..20
  const int k0 = kg * 32 + ((lane >> 4) << 3);
  const int par = lane & 15;
  float v[8];
  if (ct < 16) {
    const int col = ct * 16 + par;
#pragma unroll
    for (int j = 0; j < 8; ++j) v[j] = W1[(size_t)(k0 + j) * H_DIM + col];
  } else {
    const float* Ae = A + (size_t)(ct - 16) * D_DIM * R_DIM;
#pragma unroll
    for (int j = 0; j < 8; ++j) v[j] = Ae[(size_t)(k0 + j) * R_DIM + par];
  }
  half8 hv, lv;
#pragma unroll
  for (int j = 0; j < 8; ++j) {
    const _Float16 hh = (_Float16)v[j];
    hv[j] = hh;
    lv[j] = (_Float16)(v[j] - (float)hh);
  }
  ((half8*)Whi)[(size_t)kgct * 64 + lane] = hv;
  ((half8*)Wlo)[(size_t)kgct * 64 + lane] = lv;
}

// ---------------------------------------------------------------------------
// xgemm: grid (N_TOK/64, 3). MFMA 16x16x32 f16, split-f16 3-product
// (al*bh + ah*bl + ah*bh; the ll term ~2^-22 is dropped).
//   y in {0,1}: silu(x@W1+b1) cols [y*128,+128) stay IN REGISTERS; epilogue
//               projects through W2, reduces lanes (shfl) + waves (LDS),
//               stores partial logits plog[y][tok][5] (plain deterministic
//               stores — atomics cost ~50MB of cross-XCD line bounce in r2).
//   y == 2   : P[:, 0..79] = x @ A'  (fp32; scaled later in combine)
// Body = round-1's measured-good BK=32 loop (in-step weight loads) + XOR
// swizzle row'=row^kq (round 2 proved: bank-conflict cycles 9.4M -> 0).
// ---------------------------------------------------------------------------
__global__ __launch_bounds__(256, 3) void xgemm_kernel(
    const float* __restrict__ x, const float* __restrict__ b1,
    const _Float16* __restrict__ Whi, const _Float16* __restrict__ Wlo,
    const float* __restrict__ W2, float* __restrict__ plog,
    float* __restrict__ P) {
  __shared__ _Float16 lds[2][2][4][64][8];  // [buf][hi/lo][kq][row'][8] = 16 KB
  __shared__ float w2s[H_DIM * E_NUM];      // 5 KB, epilogue only
  __shared__ float plbuf[4][64][E_NUM];     // 5 KB, cross-wave logit reduce
  const int t = threadIdx.x;
  const int tok0 = blockIdx.x * 64;
  const int y = blockIdx.y;
  const int lane = t & 63;
  const int w = t >> 6;          // wave 0..3
  const int sr = t >> 2;         // staging row 0..63
  const int sq = t & 3;          // staging k-quarter (8 floats each)
  const int lq = lane >> 4;      // lane k-quarter
  const int lp = lane & 15;      // lane parallel index

  const float* xrow = x + (size_t)(tok0 + sr) * D_DIM + (sq << 3);

  // prologue: stage kg=0 into buf 0
  {
    float xv[8];
    *(float4*)&xv[0] = *(const float4*)(xrow);
    *(float4*)&xv[4] = *(const float4*)(xrow + 4);
    half8 hv, lv;
#pragma unroll
    for (int j = 0; j < 8; ++j) {
      const _Float16 hh = (_Float16)xv[j];
      hv[j] = hh;
      lv[j] = (_Float16)(xv[j] - (float)hh);
    }
    *(half8*)&lds[0][0][sq][sr ^ sq][0] = hv;
    *(half8*)&lds[0][1][sq][sr ^ sq][0] = lv;
  }

  const half8* WH = (const half8*)Whi;
  const half8* WL = (const half8*)Wlo;

  if (y < 2) {
    f32x4 acc[4][2];
#pragma unroll
    for (int i = 0; i < 4; ++i)
#pragma unroll
      for (int j = 0; j < 2; ++j) acc[i][j] = (f32x4)0.f;
    const int ctg0 = (y << 3) + (w << 1);  // wave owns 2 col-tiles
    int cur = 0;
    for (int kg = 0; kg < KG_N; ++kg) {
      __syncthreads();
      const bool more = (kg < KG_N - 1);
      float xv[8];
      if (more) {  // prefetch next x chunk early
        const float* src = xrow + (kg + 1) * 32;
        *(float4*)&xv[0] = *(const float4*)(src);
        *(float4*)&xv[4] = *(const float4*)(src + 4);
      }
      half8 bh[2], bl[2];
#pragma unroll
      for (int ct = 0; ct < 2; ++ct) {
        const size_t wo = ((size_t)(ctg0 + ct) * 64 + kg) * 64 + lane;
        bh[ct] = WH[wo];
        bl[ct] = WL[wo];
      }
#pragma unroll
      for (int rt = 0; rt < 4; ++rt) {
        const int r = ((rt << 4) + lp) ^ lq;
        const half8 ah = *(const half8*)&lds[cur][0][lq][r][0];
        const half8 al = *(const half8*)&lds[cur][1][lq][r][0];
#pragma unroll
        for (int ct = 0; ct < 2; ++ct) {
          acc[rt][ct] = __builtin_amdgcn_mfma_f32_16x16x32_f16(al, bh[ct], acc[rt][ct], 0, 0, 0);
          acc[rt][ct] = __builtin_amdgcn_mfma_f32_16x16x32_f16(ah, bl[ct], acc[rt][ct], 0, 0, 0);
          acc[rt][ct] = __builtin_amdgcn_mfma_f32_16x16x32_f16(ah, bh[ct], acc[rt][ct], 0, 0, 0);
        }
      }
      if (more) {
        half8 hv, lv;
#pragma unroll
        for (int j = 0; j < 8; ++j) {
          const _Float16 hh = (_Float16)xv[j];
          hv[j] = hh;
          lv[j] = (_Float16)(xv[j] - (float)hh);
        }
        *(half8*)&lds[cur ^ 1][0][sq][sr ^ sq][0] = hv;
        *(half8*)&lds[cur ^ 1][1][sq][sr ^ sq][0] = lv;
      }
      cur ^= 1;
    }

    // epilogue: silu in-register, project through W2, reduce lanes (shfl)
    // then waves (LDS), store partial logits (plain stores, deterministic).
    for (int i = t; i < H_DIM * E_NUM; i += 256) w2s[i] = W2[i];
    __syncthreads();
    const int colb = (y << 7) + (w << 5);
#pragma unroll
    for (int rt = 0; rt < 4; ++rt) {
      float pl[4][5];
#pragma unroll
      for (int rg = 0; rg < 4; ++rg)
#pragma unroll
        for (int e = 0; e < 5; ++e) pl[rg][e] = 0.f;
#pragma unroll
      for (int ct = 0; ct < 2; ++ct) {
        const int col = colb + (ct << 4) + lp;
        const float bb = b1[col];
        float w2c[5];
#pragma unroll
        for (int e = 0; e < 5; ++e) w2c[e] = w2s[col * 5 + e];
#pragma unroll
        for (int rg = 0; rg < 4; ++rg) {
          float v = acc[rt][ct][rg] + bb;
          v = v / (1.f + expf(-v));  // silu; h value, never stored
#pragma unroll
          for (int e = 0; e < 5; ++e) pl[rg][e] = fmaf(v, w2c[e], pl[rg][e]);
        }
      }
      // reduce over the 16 lp lanes (lq groups stay independent)
#pragma unroll
      for (int m = 1; m < 16; m <<= 1)
#pragma unroll
        for (int rg = 0; rg < 4; ++rg)
#pragma unroll
          for (int e = 0; e < 5; ++e) pl[rg][e] += __shfl_xor(pl[rg][e], m, 64);
      if (lp == 0) {
        const int rl0 = (rt << 4) + (lq << 2);
#pragma unroll
        for (int rg = 0; rg < 4; ++rg)
#pragma unroll
          for (int e = 0; e < 5; ++e) plbuf[w][rl0 + rg][e] = pl[rg][e];
      }
    }
    __syncthreads();
    for (int i = t; i < 64 * E_NUM; i += 256) {
      const int row = i / E_NUM;
      const int e = i - row * E_NUM;
      const float s = plbuf[0][row][e] + plbuf[1][row][e] +
                      plbuf[2][row][e] + plbuf[3][row][e];
      plog[((size_t)y * N_TOK + tok0 + row) * E_NUM + e] = s;
    }
  } else {
    // P path: wave owns 16 rows x all 80 cols (5 col-tiles)
    f32x4 acc[5];
#pragma unroll
    for (int j = 0; j < 5; ++j) acc[j] = (f32x4)0.f;
    int cur = 0;
    for (int kg = 0; kg < KG_N; ++kg) {
      __syncthreads();
      const bool more = (kg < KG_N - 1);
      float xv[8];
      if (more) {
        const float* src = xrow + (kg + 1) * 32;
        *(float4*)&xv[0] = *(const float4*)(src);
        *(float4*)&xv[4] = *(const float4*)(src + 4);
      }
      half8 bh[5], bl[5];
#pragma unroll
      for (int ct = 0; ct < 5; ++ct) {
        const size_t wo = ((size_t)(16 + ct) * 64 + kg) * 64 + lane;
        bh[ct] = WH[wo];
        bl[ct] = WL[wo];
      }
      {
        const int r = ((w << 4) + lp) ^ lq;
        const half8 ah = *(const half8*)&lds[cur][0][lq][r][0];
        const half8 al = *(const half8*)&lds[cur][1][lq][r][0];
#pragma unroll
        for (int ct = 0; ct < 5; ++ct) {
          acc[ct] = __builtin_amdgcn_mfma_f32_16x16x32_f16(al, bh[ct], acc[ct], 0, 0, 0);
          acc[ct] = __builtin_amdgcn_mfma_f32_16x16x32_f16(ah, bl[ct], acc[ct], 0, 0, 0);
          acc[ct] = __builtin_amdgcn_mfma_f32_16x16x32_f16(ah, bh[ct], acc[ct], 0, 0, 0);
        }
      }
      if (more) {
        half8 hv, lv;
#pragma unroll
        for (int j = 0; j < 8; ++j) {
          const _Float16 hh = (_Float16)xv[j];
          hv[j] = hh;
          lv[j] = (_Float16)(xv[j] - (float)hh);
        }
        *(half8*)&lds[cur ^ 1][0][sq][sr ^ sq][0] = hv;
        *(half8*)&lds[cur ^ 1][1][sq][sr ^ sq][0] = lv;
      }
      cur ^= 1;
    }
#pragma unroll
    for (int ct = 0; ct < 5; ++ct)
#pragma unroll
      for (int rg = 0; rg < 4; ++rg) {
        const int row = tok0 + (w << 4) + (lq << 2) + rg;
        P[(size_t)row * ER + (ct << 4) + lp] = acc[ct][rg];
      }
  }
}

// ---------------------------------------------------------------------------
// combine: out = base + (scaled P)[N,80] @ B[80,2048].  32-token x 256-col
// tile (acc = 8 float4 = 32 VGPR: r3's 16-float4 base-initialized acc spilled
// to scratch -> 1.48 GB of HBM write traffic). Route decision fused in a
// 32-thread prologue; P staged to LDS pre-scaled; Bm rows register
// double-buffered (bmA/bmB, statically indexed) so L2 latency hides under
// the FMA phase; base added in the epilogue only (short live range).
// ---------------------------------------------------------------------------
__global__ __launch_bounds__(256, 4) void combine_kernel(
    const float* __restrict__ P, const float* __restrict__ Bm,
    const float* __restrict__ base, const float* __restrict__ plog,
    const float* __restrict__ b2, float* __restrict__ out) {
  __shared__ float Pl[32][80];  // pre-scaled P tile, 10 KB
  __shared__ float sc[32][5];   // per-token per-expert scale
  const int t = threadIdx.x;
  const int wg = __builtin_amdgcn_readfirstlane(t >> 6);  // wave-uniform
  const int c4 = ((blockIdx.x & 7) << 8) + ((t & 63) << 2);
  const int tokb = (blockIdx.x >> 3) << 5;
  const int r0 = wg << 3;  // 8 rows per wave

  if (t < 32) {
    const float* p0 = plog + (size_t)(tokb + t) * E_NUM;
    const float* p1 = plog + ((size_t)N_TOK + tokb + t) * E_NUM;
    float lg[5];
#pragma unroll
    for (int e = 0; e < 5; ++e) lg[e] = p0[e] + p1[e] + b2[e];
    int e0 = 0;
#pragma unroll
    for (int e = 1; e < 5; ++e) if (lg[e] > lg[e0]) e0 = e;
    int e1 = (e0 == 0) ? 1 : 0;
#pragma unroll
    for (int e = 0; e < 5; ++e) if (e != e0 && lg[e] > lg[e1]) e1 = e;
    const float qq = expf(lg[e1] - lg[e0]);  // <= 1, stable
    const float s0 = 2.f / (1.f + qq);       // SCALING * w0_normalized
    const float s1 = qq * s0;                // SCALING * w1_normalized
#pragma unroll
    for (int e = 0; e < 5; ++e)
      sc[t][e] = (e == e0) ? s0 : ((e == e1) ? s1 : 0.f);
  }
  __syncthreads();
  // stage P scaled: 640 float4 chunks (32 rows x 20), threads cover 3 rounds
  for (int idx = t; idx < 640; idx += 256) {
    const int row = idx / 20;
    const int off = (idx % 20) << 2;
    float4 v = *(const float4*)(P + (size_t)(tokb + row) * ER + off);
    v.x *= sc[row][(off + 0) >> 4];
    v.y *= sc[row][(off + 1) >> 4];
    v.z *= sc[row][(off + 2) >> 4];
    v.w *= sc[row][(off + 3) >> 4];
    *(float4*)&Pl[row][off] = v;
  }
  __syncthreads();

  float4 acc[8];
#pragma unroll
  for (int i = 0; i < 8; ++i) acc[i] = make_float4(0.f, 0.f, 0.f, 0.f);

  float4 bmA[4], bmB[4];
#pragma unroll
  for (int r = 0; r < 4; ++r)
    bmA[r] = *(const float4*)(Bm + (size_t)r * D_DIM + c4);

  for (int k0 = 0; k0 < ER; k0 += 8) {
    // prefetch rows k0+4..k0+7 while computing with bmA (k0..k0+3)
#pragma unroll
    for (int r = 0; r < 4; ++r)
      bmB[r] = *(const float4*)(Bm + (size_t)(k0 + 4 + r) * D_DIM + c4);
#pragma unroll
    for (int i = 0; i < 8; ++i) {
      float pv[4];
      *(float4*)pv = *(const float4*)&Pl[r0 + i][k0];  // uniform -> broadcast
      acc[i].x = fmaf(pv[0], bmA[0].x, fmaf(pv[1], bmA[1].x, fmaf(pv[2], bmA[2].x, fmaf(pv[3], bmA[3].x, acc[i].x))));
      acc[i].y = fmaf(pv[0], bmA[0].y, fmaf(pv[1], bmA[1].y, fmaf(pv[2], bmA[2].y, fmaf(pv[3], bmA[3].y, acc[i].y))));
      acc[i].z = fmaf(pv[0], bmA[0].z, fmaf(pv[1], bmA[1].z, fmaf(pv[2], bmA[2].z, fmaf(pv[3], bmA[3].z, acc[i].z))));
      acc[i].w = fmaf(pv[0], bmA[0].w, fmaf(pv[1], bmA[1].w, fmaf(pv[2], bmA[2].w, fmaf(pv[3], bmA[3].w, acc[i].w))));
    }
    if (k0 + 8 < ER) {
#pragma unroll
      for (int r = 0; r < 4; ++r)
        bmA[r] = *(const float4*)(Bm + (size_t)(k0 + 8 + r) * D_DIM + c4);
    }
#pragma unroll
    for (int i = 0; i < 8; ++i) {
      float pv[4];
      *(float4*)pv = *(const float4*)&Pl[r0 + i][k0 + 4];
      acc[i].x = fmaf(pv[0], bmB[0].x, fmaf(pv[1], bmB[1].x, fmaf(pv[2], bmB[2].x, fmaf(pv[3], bmB[3].x, acc[i].x))));
      acc[i].y = fmaf(pv[0], bmB[0].y, fmaf(pv[1], bmB[1].y, fmaf(pv[2], bmB[2].y, fmaf(pv[3], bmB[3].y, acc[i].y))));
      acc[i].z = fmaf(pv[0], bmB[0].z, fmaf(pv[1], bmB[1].z, fmaf(pv[2], bmB[2].z, fmaf(pv[3], bmB[3].z, acc[i].z))));
      acc[i].w = fmaf(pv[0], bmB[0].w, fmaf(pv[1], bmB[1].w, fmaf(pv[2], bmB[2].w, fmaf(pv[3], bmB[3].w, acc[i].w))));
    }
  }

#pragma unroll
  for (int i = 0; i < 8; ++i) {
    const size_t o = (size_t)(tokb + r0 + i) * D_DIM + c4;
    const float4 b = *(const float4*)(base + o);
    float4 r;
    r.x = acc[i].x + b.x;
    r.y = acc[i].y + b.y;
    r.z = acc[i].z + b.z;
    r.w = acc[i].w + b.w;
    *(float4*)(out + o) = r;
  }
}

// ---------------------------------------------------------------------------
extern "C" void kernel_launch(void* const* d_in, const int* in_sizes, int n_in,
                              void* d_out, int out_size, void* d_ws,
                              size_t ws_size, hipStream_t stream) {
  const float* x  = (const float*)d_in[0];
  const float* bo = (const float*)d_in[1];
  const float* A  = (const float*)d_in[2];
  const float* Bm = (const float*)d_in[3];
  const float* W1 = (const float*)d_in[4];
  const float* b1 = (const float*)d_in[5];
  const float* W2 = (const float*)d_in[6];
  const float* b2 = (const float*)d_in[7];
  float* out = (float*)d_out;

  char* ws = (char*)d_ws;
  float* P = (float*)ws;                                  // [N][80] f32 = 5.25 MiB
  _Float16* Whi = (_Float16*)(ws + 5242880);              // 1.31 MiB
  _Float16* Wlo = (_Float16*)(ws + 5242880 + 1376256);    // 1.31 MiB
  float* plog = (float*)(ws + 5242880 + 2 * 1376256);     // [2][N][5] = 640 KiB

  pack_w_kernel<<<336, 256, 0, stream>>>(W1, A, Whi, Wlo);
  xgemm_kernel<<<dim3(N_TOK / 64, 3), 256, 0, stream>>>(x, b1, Whi, Wlo, W2,
                                                        plog, P);
  combine_kernel<<<(N_TOK / 32) * (D_DIM / 256), 256, 0, stream>>>(
      P, Bm, bo, plog, b2, out);
}

// Round 5
// 386.504 us; speedup vs baseline: 2.1268x; 1.1435x over previous
//
#include <hip/hip_runtime.h>
#include <math.h>

// Problem constants (fixed by setup_inputs)
#define N_TOK 16384   // B*S
#define D_DIM 2048
#define H_DIM 256
#define E_NUM 5
#define R_DIM 16
#define ER 80         // E*R

#define NCT 21        // 16 W1 col-tiles + 5 A' col-tiles (16 cols each)
#define KG_N 64       // 2048 / 32  (BK = 32)

typedef _Float16 half8 __attribute__((ext_vector_type(8)));
typedef float f32x4 __attribute__((ext_vector_type(4)));

// ---------------------------------------------------------------------------
// pack_w: three packings in one launch (432 blocks):
//  idx <  86016: W1[2048][256] and A'[2048][80] -> f16 hi/lo fragment arrays
//     Wp[((ct*64+kg)*64+l)*8+j] = W[kg*32 + (l>>4)*8 + j][ct*16 + (l&15)]
//  idx >= 86016: B[80][2048] -> f16 (hi only) fragment array Bf, K zero-padded
//     to 96: Bf[((ct*3+s)*64+l)*8+j] = B[s*32+(l>>4)*8+j][ct*16+(l&15)]
// Router needs split-f16 (hi/lo, 3-product ~ fp32); P and combine tolerate
// single-product f16 (error ~5e-4 << 0.0156 tolerance).
// ---------------------------------------------------------------------------
__global__ __launch_bounds__(256) void pack_w_kernel(
    const float* __restrict__ W1, const float* __restrict__ A,
    const float* __restrict__ Bm, _Float16* __restrict__ Whi,
    _Float16* __restrict__ Wlo, _Float16* __restrict__ Bf) {
  const int idx = blockIdx.x * 256 + threadIdx.x;  // 432*256 = 110592
  const int lane = idx & 63;
  if (idx < 86016) {
    const int kgct = idx >> 6;              // ct*64 + kg, 0..1343
    const int kg = kgct & 63;
    const int ct = kgct >> 6;               // 0..20
    const int k0 = kg * 32 + ((lane >> 4) << 3);
    const int par = lane & 15;
    float v[8];
    if (ct < 16) {
      const int col = ct * 16 + par;
#pragma unroll
      for (int j = 0; j < 8; ++j) v[j] = W1[(size_t)(k0 + j) * H_DIM + col];
    } else {
      const float* Ae = A + (size_t)(ct - 16) * D_DIM * R_DIM;
#pragma unroll
      for (int j = 0; j < 8; ++j) v[j] = Ae[(size_t)(k0 + j) * R_DIM + par];
    }
    half8 hv, lv;
#pragma unroll
    for (int j = 0; j < 8; ++j) {
      const _Float16 hh = (_Float16)v[j];
      hv[j] = hh;
      lv[j] = (_Float16)(v[j] - (float)hh);
    }
    ((half8*)Whi)[(size_t)kgct * 64 + lane] = hv;
    ((half8*)Wlo)[(size_t)kgct * 64 + lane] = lv;
  } else {
    const int u = (idx - 86016) >> 6;       // ct*3 + s, 0..383
    const int s = u % 3;
    const int ct = u / 3;                   // 0..127
    const int col = ct * 16 + (lane & 15);
    const int kb = s * 32 + ((lane >> 4) << 3);
    half8 hv;
#pragma unroll
    for (int j = 0; j < 8; ++j) {
      const int k = kb + j;
      hv[j] = (k < ER) ? (_Float16)Bm[(size_t)k * D_DIM + col] : (_Float16)0.f;
    }
    ((half8*)Bf)[(size_t)u * 64 + lane] = hv;
  }
}

// ---------------------------------------------------------------------------
// xgemm: grid (N_TOK/64, 3). MFMA 16x16x32 f16.
//   y in {0,1}: split-f16 3-product router half: silu(x@W1+b1) in registers,
//               projected through W2, lane+wave reduced, partial logits
//               stored to plog[y][tok][5] (plain deterministic stores).
//   y == 2   : P = x @ A', SINGLE-product f16 (P is flip-insensitive;
//               error ~2e-4). 1/3 the MFMAs, 1/2 the weight bytes.
// KEY CHANGE vs r4: weights are REGISTER DOUBLE-BUFFERED one K-step ahead
// (sets A/B, kg-unrolled x2). r4 issued x (HBM, slow) before weights (L2)
// in-step; vmcnt FIFO then put the x latency on the MFMA critical path
// every step (~5500cy/step vs ~350cy of MFMA work). Now MFMAs start with
// zero vmem wait; x latency is absorbed by the MFMA phase before ds_write.
// ---------------------------------------------------------------------------
#define W_BODY(USE_H, USE_L, PRE_H, PRE_L, KG)                               \
  __syncthreads();                                                           \
  {                                                                          \
    const int kn = (KG) + 1;                                                 \
    if (kn < KG_N) {                                                         \
      _Pragma("unroll") for (int ct = 0; ct < 2; ++ct) {                     \
        const size_t wo = ((size_t)(ctg0 + ct) * 64 + kn) * 64 + lane;       \
        PRE_H[ct] = WH[wo];                                                  \
        PRE_L[ct] = WL[wo];                                                  \
      }                                                                      \
    }                                                                        \
    float xv[8];                                                             \
    const bool more = (KG) < KG_N - 1;                                       \
    if (more) {                                                              \
      const float* src = xrow + ((KG) + 1) * 32;                             \
      *(float4*)&xv[0] = *(const float4*)(src);                              \
      *(float4*)&xv[4] = *(const float4*)(src + 4);                          \
    }                                                                        \
    _Pragma("unroll") for (int rt = 0; rt < 4; ++rt) {                       \
      const int r = ((rt << 4) + lp) ^ lq;                                   \
      const half8 ah = *(const half8*)&lds[cur][0][lq][r][0];                \
      const half8 al = *(const half8*)&lds[cur][1][lq][r][0];                \
      _Pragma("unroll") for (int ct = 0; ct < 2; ++ct) {                     \
        acc[rt][ct] = __builtin_amdgcn_mfma_f32_16x16x32_f16(                \
            al, USE_H[ct], acc[rt][ct], 0, 0, 0);                            \
        acc[rt][ct] = __builtin_amdgcn_mfma_f32_16x16x32_f16(                \
            ah, USE_L[ct], acc[rt][ct], 0, 0, 0);                            \
        acc[rt][ct] = __builtin_amdgcn_mfma_f32_16x16x32_f16(                \
            ah, USE_H[ct], acc[rt][ct], 0, 0, 0);                            \
      }                                                                      \
    }                                                                        \
    if (more) {                                                              \
      half8 hv, lv;                                                          \
      _Pragma("unroll") for (int j = 0; j < 8; ++j) {                        \
        const _Float16 hh = (_Float16)xv[j];                                 \
        hv[j] = hh;                                                          \
        lv[j] = (_Float16)(xv[j] - (float)hh);                               \
      }                                                                      \
      *(half8*)&lds[cur ^ 1][0][sq][sr ^ sq][0] = hv;                        \
      *(half8*)&lds[cur ^ 1][1][sq][sr ^ sq][0] = lv;                        \
    }                                                                        \
    cur ^= 1;                                                                \
  }

#define P_BODY(USE_H, PRE_H, KG)                                             \
  __syncthreads();                                                           \
  {                                                                          \
    const int kn = (KG) + 1;                                                 \
    if (kn < KG_N) {                                                         \
      _Pragma("unroll") for (int ct = 0; ct < 5; ++ct) {                     \
        const size_t wo = ((size_t)(16 + ct) * 64 + kn) * 64 + lane;         \
        PRE_H[ct] = WH[wo];                                                  \
      }                                                                      \
    }                                                                        \
    float xv[8];                                                             \
    const bool more = (KG) < KG_N - 1;                                       \
    if (more) {                                                              \
      const float* src = xrow + ((KG) + 1) * 32;                             \
      *(float4*)&xv[0] = *(const float4*)(src);                              \
      *(float4*)&xv[4] = *(const float4*)(src + 4);                          \
    }                                                                        \
    {                                                                        \
      const int r = ((w << 4) + lp) ^ lq;                                    \
      const half8 ah = *(const half8*)&lds[cur][0][lq][r][0];                \
      _Pragma("unroll") for (int ct = 0; ct < 5; ++ct) {                     \
        acc[ct] = __builtin_amdgcn_mfma_f32_16x16x32_f16(                    \
            ah, USE_H[ct], acc[ct], 0, 0, 0);                                \
      }                                                                      \
    }                                                                        \
    if (more) {                                                              \
      half8 hv;                                                              \
      _Pragma("unroll") for (int j = 0; j < 8; ++j) {                        \
        hv[j] = (_Float16)xv[j];                                             \
      }                                                                      \
      *(half8*)&lds[cur ^ 1][0][sq][sr ^ sq][0] = hv;                        \
    }                                                                        \
    cur ^= 1;                                                                \
  }

__global__ __launch_bounds__(256, 3) void xgemm_kernel(
    const float* __restrict__ x, const float* __restrict__ b1,
    const _Float16* __restrict__ Whi, const _Float16* __restrict__ Wlo,
    const float* __restrict__ W2, float* __restrict__ plog,
    float* __restrict__ P) {
  __shared__ _Float16 lds[2][2][4][64][8];  // [buf][hi/lo][kq][row'][8] = 16 KB
  __shared__ float w2s[H_DIM * E_NUM];      // 5 KB, epilogue only
  __shared__ float plbuf[4][64][E_NUM];     // 5 KB, cross-wave logit reduce
  const int t = threadIdx.x;
  const int tok0 = blockIdx.x * 64;
  const int y = blockIdx.y;
  const int lane = t & 63;
  const int w = t >> 6;          // wave 0..3
  const int sr = t >> 2;         // staging row 0..63
  const int sq = t & 3;          // staging k-quarter (8 floats each)
  const int lq = lane >> 4;      // lane k-quarter
  const int lp = lane & 15;      // lane parallel index

  const float* xrow = x + (size_t)(tok0 + sr) * D_DIM + (sq << 3);

  // prologue: stage kg=0 into buf 0 (lo plane only needed by y<2)
  {
    float xv[8];
    *(float4*)&xv[0] = *(const float4*)(xrow);
    *(float4*)&xv[4] = *(const float4*)(xrow + 4);
    half8 hv, lv;
#pragma unroll
    for (int j = 0; j < 8; ++j) {
      const _Float16 hh = (_Float16)xv[j];
      hv[j] = hh;
      lv[j] = (_Float16)(xv[j] - (float)hh);
    }
    *(half8*)&lds[0][0][sq][sr ^ sq][0] = hv;
    if (y < 2) *(half8*)&lds[0][1][sq][sr ^ sq][0] = lv;
  }

  const half8* WH = (const half8*)Whi;
  const half8* WL = (const half8*)Wlo;

  if (y < 2) {
    f32x4 acc[4][2];
#pragma unroll
    for (int i = 0; i < 4; ++i)
#pragma unroll
      for (int j = 0; j < 2; ++j) acc[i][j] = (f32x4)0.f;
    const int ctg0 = (y << 3) + (w << 1);  // wave owns 2 col-tiles

    half8 bhA[2], blA[2], bhB[2], blB[2];
#pragma unroll
    for (int ct = 0; ct < 2; ++ct) {  // preload kg=0 -> set A
      const size_t wo = ((size_t)(ctg0 + ct) * 64 + 0) * 64 + lane;
      bhA[ct] = WH[wo];
      blA[ct] = WL[wo];
    }

    int cur = 0;
    for (int kg = 0; kg < KG_N; kg += 2) {
      W_BODY(bhA, blA, bhB, blB, kg)
      W_BODY(bhB, blB, bhA, blA, kg + 1)
    }

    // epilogue: silu in-register, project through W2, reduce lanes (shfl)
    // then waves (LDS), store partial logits (plain stores, deterministic).
    for (int i = t; i < H_DIM * E_NUM; i += 256) w2s[i] = W2[i];
    __syncthreads();
    const int colb = (y << 7) + (w << 5);
#pragma unroll
    for (int rt = 0; rt < 4; ++rt) {
      float pl[4][5];
#pragma unroll
      for (int rg = 0; rg < 4; ++rg)
#pragma unroll
        for (int e = 0; e < 5; ++e) pl[rg][e] = 0.f;
#pragma unroll
      for (int ct = 0; ct < 2; ++ct) {
        const int col = colb + (ct << 4) + lp;
        const float bb = b1[col];
        float w2c[5];
#pragma unroll
        for (int e = 0; e < 5; ++e) w2c[e] = w2s[col * 5 + e];
#pragma unroll
        for (int rg = 0; rg < 4; ++rg) {
          float v = acc[rt][ct][rg] + bb;
          v = v / (1.f + expf(-v));  // silu; h value, never stored
#pragma unroll
          for (int e = 0; e < 5; ++e) pl[rg][e] = fmaf(v, w2c[e], pl[rg][e]);
        }
      }
#pragma unroll
      for (int m = 1; m < 16; m <<= 1)
#pragma unroll
        for (int rg = 0; rg < 4; ++rg)
#pragma unroll
          for (int e = 0; e < 5; ++e) pl[rg][e] += __shfl_xor(pl[rg][e], m, 64);
      if (lp == 0) {
        const int rl0 = (rt << 4) + (lq << 2);
#pragma unroll
        for (int rg = 0; rg < 4; ++rg)
#pragma unroll
          for (int e = 0; e < 5; ++e) plbuf[w][rl0 + rg][e] = pl[rg][e];
      }
    }
    __syncthreads();
    for (int i = t; i < 64 * E_NUM; i += 256) {
      const int row = i / E_NUM;
      const int e = i - row * E_NUM;
      const float s = plbuf[0][row][e] + plbuf[1][row][e] +
                      plbuf[2][row][e] + plbuf[3][row][e];
      plog[((size_t)y * N_TOK + tok0 + row) * E_NUM + e] = s;
    }
  } else {
    // P path: wave owns 16 rows x all 80 cols; single-product f16.
    f32x4 acc[5];
#pragma unroll
    for (int j = 0; j < 5; ++j) acc[j] = (f32x4)0.f;

    half8 bhA[5], bhB[5];
#pragma unroll
    for (int ct = 0; ct < 5; ++ct) {  // preload kg=0 -> set A
      const size_t wo = ((size_t)(16 + ct) * 64 + 0) * 64 + lane;
      bhA[ct] = WH[wo];
    }

    int cur = 0;
    for (int kg = 0; kg < KG_N; kg += 2) {
      P_BODY(bhA, bhB, kg)
      P_BODY(bhB, bhA, kg + 1)
    }
#pragma unroll
    for (int ct = 0; ct < 5; ++ct)
#pragma unroll
      for (int rg = 0; rg < 4; ++rg) {
        const int row = tok0 + (w << 4) + (lq << 2) + rg;
        P[(size_t)row * ER + (ct << 4) + lp] = acc[ct][rg];
      }
  }
}

// ---------------------------------------------------------------------------
// combine: out = base + (scaled P)[N,80] @ B[80,2048], now on MFMA f16.
// Block = 32 tok x 256 col (4096 blocks). Sequence: issue P loads to regs +
// all 12 B-fragments (L2-resident, 16B/lane) up front; t<32 computes top-2
// scales from plog; barrier; scale+cvt P into LDS f16 [32][104] (208B row
// stride: 16B-aligned, ~2-way banks; K zero-padded 80->96); barrier; 24
// MFMAs; epilogue adds base (coalesced 64B/16-lane segments).
// Memory floor ~262 MB ~= 42 us.
// ---------------------------------------------------------------------------
__global__ __launch_bounds__(256, 2) void combine_kernel(
    const float* __restrict__ P, const _Float16* __restrict__ Bf,
    const float* __restrict__ base, const float* __restrict__ plog,
    const float* __restrict__ b2, float* __restrict__ out) {
  __shared__ _Float16 Pl[32][104];  // f16 scaled P tile, 6.5 KB
  __shared__ float sc[32][5];       // per-token per-expert scale
  const int t = threadIdx.x;
  const int lane = t & 63;
  const int w = t >> 6;
  const int bx = blockIdx.x;
  const int tokb = (bx >> 3) << 5;
  const int colb = (bx & 7) << 8;
  const int lp = lane & 15;
  const int lq = lane >> 4;

  // P tile loads into regs (unit u covers row u/12, 8-col chunk (u%12)*8)
  const int u0r = t / 12, u0c = (t % 12) << 3;
  float4 pa0 = make_float4(0.f, 0.f, 0.f, 0.f), pb0 = pa0;
  if (u0c < ER) {
    const float* pr = P + (size_t)(tokb + u0r) * ER + u0c;
    pa0 = *(const float4*)pr;
    pb0 = *(const float4*)(pr + 4);
  }
  const int u1 = t + 256;
  const int u1r = u1 / 12, u1c = (u1 % 12) << 3;
  const bool has1 = (t < 128);
  float4 pa1 = make_float4(0.f, 0.f, 0.f, 0.f), pb1 = pa1;
  if (has1 && u1c < ER) {
    const float* pr = P + (size_t)(tokb + u1r) * ER + u1c;
    pa1 = *(const float4*)pr;
    pb1 = *(const float4*)(pr + 4);
  }

  // B fragments: 4 col-tiles x 3 K-steps per wave, issued up front
  const half8* BH = (const half8*)Bf;
  const int ctg = (colb >> 4) + (w << 2);
  half8 bf[4][3];
#pragma unroll
  for (int ct = 0; ct < 4; ++ct)
#pragma unroll
    for (int s = 0; s < 3; ++s)
      bf[ct][s] = BH[(size_t)((ctg + ct) * 3 + s) * 64 + lane];

  if (t < 32) {
    const float* p0 = plog + (size_t)(tokb + t) * E_NUM;
    const float* p1 = plog + ((size_t)N_TOK + tokb + t) * E_NUM;
    float lg[5];
#pragma unroll
    for (int e = 0; e < 5; ++e) lg[e] = p0[e] + p1[e] + b2[e];
    int e0 = 0;
#pragma unroll
    for (int e = 1; e < 5; ++e) if (lg[e] > lg[e0]) e0 = e;
    int e1 = (e0 == 0) ? 1 : 0;
#pragma unroll
    for (int e = 0; e < 5; ++e) if (e != e0 && lg[e] > lg[e1]) e1 = e;
    const float qq = expf(lg[e1] - lg[e0]);  // <= 1, stable
    const float s0 = 2.f / (1.f + qq);       // SCALING * w0_normalized
    const float s1 = qq * s0;                // SCALING * w1_normalized
#pragma unroll
    for (int e = 0; e < 5; ++e)
      sc[t][e] = (e == e0) ? s0 : ((e == e1) ? s1 : 0.f);
  }
  __syncthreads();
  {  // scale + cvt f16 + store to Pl (chunk is within one expert: c%16 in {0,8})
    const float s0 = (u0c < ER) ? sc[u0r][u0c >> 4] : 0.f;
    half8 hv;
    hv[0] = (_Float16)(pa0.x * s0); hv[1] = (_Float16)(pa0.y * s0);
    hv[2] = (_Float16)(pa0.z * s0); hv[3] = (_Float16)(pa0.w * s0);
    hv[4] = (_Float16)(pb0.x * s0); hv[5] = (_Float16)(pb0.y * s0);
    hv[6] = (_Float16)(pb0.z * s0); hv[7] = (_Float16)(pb0.w * s0);
    *(half8*)&Pl[u0r][u0c] = hv;
    if (has1) {
      const float s1v = (u1c < ER) ? sc[u1r][u1c >> 4] : 0.f;
      half8 h2;
      h2[0] = (_Float16)(pa1.x * s1v); h2[1] = (_Float16)(pa1.y * s1v);
      h2[2] = (_Float16)(pa1.z * s1v); h2[3] = (_Float16)(pa1.w * s1v);
      h2[4] = (_Float16)(pb1.x * s1v); h2[5] = (_Float16)(pb1.y * s1v);
      h2[6] = (_Float16)(pb1.z * s1v); h2[7] = (_Float16)(pb1.w * s1v);
      *(half8*)&Pl[u1r][u1c] = h2;
    }
  }
  __syncthreads();

  f32x4 acc[2][4];
#pragma unroll
  for (int rt = 0; rt < 2; ++rt)
#pragma unroll
    for (int ct = 0; ct < 4; ++ct) acc[rt][ct] = (f32x4)0.f;

#pragma unroll
  for (int rt = 0; rt < 2; ++rt)
#pragma unroll
    for (int s = 0; s < 3; ++s) {
      const half8 a = *(const half8*)&Pl[(rt << 4) + lp][(s << 5) + (lq << 3)];
#pragma unroll
      for (int ct = 0; ct < 4; ++ct)
        acc[rt][ct] = __builtin_amdgcn_mfma_f32_16x16x32_f16(
            a, bf[ct][s], acc[rt][ct], 0, 0, 0);
    }

  // epilogue: C[row = (lane>>4)*4+rg, col = lane&15] per 16x16 tile
#pragma unroll
  for (int rt = 0; rt < 2; ++rt)
#pragma unroll
    for (int ct = 0; ct < 4; ++ct) {
      const int col = colb + (w << 6) + (ct << 4) + lp;
#pragma unroll
      for (int rg = 0; rg < 4; ++rg) {
        const int row = tokb + (rt << 4) + (lq << 2) + rg;
        const size_t o = (size_t)row * D_DIM + col;
        out[o] = acc[rt][ct][rg] + base[o];
      }
    }
}

// ---------------------------------------------------------------------------
extern "C" void kernel_launch(void* const* d_in, const int* in_sizes, int n_in,
                              void* d_out, int out_size, void* d_ws,
                              size_t ws_size, hipStream_t stream) {
  const float* x  = (const float*)d_in[0];
  const float* bo = (const float*)d_in[1];
  const float* A  = (const float*)d_in[2];
  const float* Bm = (const float*)d_in[3];
  const float* W1 = (const float*)d_in[4];
  const float* b1 = (const float*)d_in[5];
  const float* W2 = (const float*)d_in[6];
  const float* b2 = (const float*)d_in[7];
  float* out = (float*)d_out;

  char* ws = (char*)d_ws;
  float* P = (float*)ws;                                 // [N][80] = 5.25 MiB
  _Float16* Whi = (_Float16*)(ws + 5242880);             // 1.31 MiB
  _Float16* Wlo = (_Float16*)(ws + 5242880 + 1376256);   // 1.31 MiB
  float* plog = (float*)(ws + 5242880 + 2 * 1376256);    // [2][N][5] = 640 KiB
  _Float16* Bf = (_Float16*)(ws + 5242880 + 2 * 1376256 + 655360);  // 384 KiB

  pack_w_kernel<<<432, 256, 0, stream>>>(W1, A, Bm, Whi, Wlo, Bf);
  xgemm_kernel<<<dim3(N_TOK / 64, 3), 256, 0, stream>>>(x, b1, Whi, Wlo, W2,
                                                        plog, P);
  combine_kernel<<<(N_TOK / 32) * (D_DIM / 256), 256, 0, stream>>>(
      P, Bf, bo, plog, b2, out);
}